// Round 1
// baseline (294.300 us; speedup 1.0000x reference)
//
#include <hip/hip_runtime.h>
#include <stdint.h>

// GeAT single-head layer, B=32 N=512 D=128 T=8.
// Formulation: S_t = X @ (Qw^T a_t) + (Qb a_t);  dst = X@Kw^T+Kb;  val = X@Vw^T+Vb
// att_raw[b,n,m] = S_{clamp(e,0)}[b,n,:] . dst[b,m,:]  -> mask(e==-1) -> leaky -> softmax(m)
// out = (att @ val) @ Pw^T + Pb
// All matmuls: fp32 emulated as hi/lo bf16 split, 3x mfma_f32_16x16x32_bf16.
// Workspace requirement: ~135 MB.

typedef short bf16x8 __attribute__((ext_vector_type(8)));
typedef float f32x4 __attribute__((ext_vector_type(4)));
typedef unsigned short u16;
typedef unsigned int u32;

__device__ __forceinline__ u16 f2bf(float x) {
    union { float f; u32 u; } v; v.f = x;
    u32 r = v.u + 0x7FFFu + ((v.u >> 16) & 1u);   // RNE truncate f32->bf16
    return (u16)(r >> 16);
}
__device__ __forceinline__ float bf2f(u16 h) {
    union { u32 u; float f; } v; v.u = ((u32)h) << 16; return v.f;
}
__device__ __forceinline__ void split_hl(float x, u16& h, u16& l) {
    h = f2bf(x);
    l = f2bf(x - bf2f(h));
}
__device__ __forceinline__ f32x4 mfma16(bf16x8 a, bf16x8 b, f32x4 c) {
    return __builtin_amdgcn_mfma_f32_16x16x32_bf16(a, b, c, 0, 0, 0);
}

// ---------------------------------------------------------------------------
// prep: build WcatT (1408 x 128) hi/lo bf16 and bcat (1408) f32.
// rows [0,128): Kw rows (dst)   [128,256): Vw rows (val)
// rows [256,1280): row 256+128t+j = (Qw^T a_t) column j, i.e. sum_e Qw[e][d]*a[e][j][t]
// rows [1280,1408): Pw rows (final projection)
// ---------------------------------------------------------------------------
__global__ void prep_kernel(const float* __restrict__ Qw, const float* __restrict__ Qb,
                            const float* __restrict__ Kw, const float* __restrict__ Kb,
                            const float* __restrict__ Vw, const float* __restrict__ Vb,
                            const float* __restrict__ Aa, const float* __restrict__ Pw,
                            const float* __restrict__ Pb,
                            u16* __restrict__ WH, u16* __restrict__ WL,
                            float* __restrict__ bcat) {
    int gid = blockIdx.x * 256 + threadIdx.x;
    if (gid >= 1408 * 128) return;
    int j = gid >> 7, d = gid & 127;
    float v, bias = 0.f;
    if (j < 128) { v = Kw[j * 128 + d]; bias = Kb[j]; }
    else if (j < 256) { int jj = j - 128; v = Vw[jj * 128 + d]; bias = Vb[jj]; }
    else if (j < 1280) {
        int r = j - 256, t = r >> 7, jj = r & 127;
        float s = 0.f, bs = 0.f;
        for (int e = 0; e < 128; e++) {
            float av = Aa[(e * 128 + jj) * 8 + t];
            s += Qw[e * 128 + d] * av;
            bs += Qb[e] * av;
        }
        v = s; bias = bs;
    } else { int jj = j - 1280; v = Pw[jj * 128 + d]; bias = Pb[jj]; }
    u16 h, l; split_hl(v, h, l);
    WH[gid] = h; WL[gid] = l;
    if (d == 0) bcat[j] = bias;
}

// ---------------------------------------------------------------------------
// detect: edges buffer int32 vs int64 layout. If int64, every odd 32-bit word
// (hi word of a value in [-1,7]) is 0 or -1. 512 samples => deterministic.
// ---------------------------------------------------------------------------
__global__ void detect_kernel(const int* __restrict__ E, int* __restrict__ flag) {
    __shared__ int bad;
    if (threadIdx.x == 0) bad = 0;
    __syncthreads();
    int w0 = E[2 * threadIdx.x + 1];
    int w1 = E[2 * (threadIdx.x + 256) + 1];
    if (!(w0 == 0 || w0 == -1) || !(w1 == 0 || w1 == -1)) atomicOr(&bad, 1);
    __syncthreads();
    if (threadIdx.x == 0) *flag = (bad ? 0 : 1);   // 1 => int64 layout
}

// ---------------------------------------------------------------------------
// gemm1: C(16384 x 1280) = X(16384x128) @ WcatT^T + bcat, split hi/lo bf16.
// val columns [128,256) are written TRANSPOSED into VTH/VTL (B,128,512) for PV.
// Block: 64x64 tile, 4 waves of 32x32, K=128 staged once. LDS 64KB, swizzled.
// ---------------------------------------------------------------------------
__launch_bounds__(256, 2)
__global__ void gemm1_kernel(const float* __restrict__ X,
                             const u16* __restrict__ WH, const u16* __restrict__ WL,
                             const float* __restrict__ bcat,
                             u16* __restrict__ CH, u16* __restrict__ CL,
                             u16* __restrict__ VTH, u16* __restrict__ VTL) {
    const int j0 = blockIdx.x * 64;
    const int g0 = blockIdx.y * 64;
    __shared__ u16 AH[64 * 128], AL[64 * 128], BH[64 * 128], BL[64 * 128];
    const int tid = threadIdx.x;
    {
        const float4* Xv = (const float4*)(X + (size_t)g0 * 128);
        #pragma unroll
        for (int i = 0; i < 8; i++) {
            int idx = tid + i * 256;              // 2048 float4 = 64 rows x 32
            float4 x = Xv[idx];
            int row = idx >> 5, c4 = idx & 31;
            int boff = (row * 256 + c4 * 8) ^ ((row & 7) << 4);
            u16* ph = (u16*)((char*)AH + boff);
            u16* pl = (u16*)((char*)AL + boff);
            const float* xf = (const float*)&x;
            #pragma unroll
            for (int q = 0; q < 4; q++) { u16 h, l; split_hl(xf[q], h, l); ph[q] = h; pl[q] = l; }
        }
        const uint4* bh = (const uint4*)(WH + (size_t)j0 * 128);
        const uint4* bl = (const uint4*)(WL + (size_t)j0 * 128);
        #pragma unroll
        for (int i = 0; i < 4; i++) {
            int idx = tid + i * 256;              // 1024 16B chunks = 64 rows x 16
            int row = idx >> 4, ch = idx & 15;
            int boff = (row * 256 + ch * 16) ^ ((row & 7) << 4);
            *(uint4*)((char*)BH + boff) = bh[idx];
            *(uint4*)((char*)BL + boff) = bl[idx];
        }
    }
    __syncthreads();
    const int wid = tid >> 6, lane = tid & 63;
    const int wr = (wid >> 1) * 32, wc = (wid & 1) * 32;
    const int lr = lane & 15, lg = lane >> 4;
    f32x4 acc[2][2] = {};
    #pragma unroll
    for (int ks = 0; ks < 4; ks++) {
        const int kb2 = (ks * 32 + lg * 8) * 2;
        bf16x8 afh[2], afl[2], bfh[2], bfl[2];
        #pragma unroll
        for (int r = 0; r < 2; r++) {
            int row = wr + r * 16 + lr;
            int boff = (row * 256 + kb2) ^ ((row & 7) << 4);
            afh[r] = *(const bf16x8*)((const char*)AH + boff);
            afl[r] = *(const bf16x8*)((const char*)AL + boff);
        }
        #pragma unroll
        for (int c = 0; c < 2; c++) {
            int row = wc + c * 16 + lr;
            int boff = (row * 256 + kb2) ^ ((row & 7) << 4);
            bfh[c] = *(const bf16x8*)((const char*)BH + boff);
            bfl[c] = *(const bf16x8*)((const char*)BL + boff);
        }
        #pragma unroll
        for (int r = 0; r < 2; r++)
        #pragma unroll
        for (int c = 0; c < 2; c++) {
            acc[r][c] = mfma16(afh[r], bfh[c], acc[r][c]);
            acc[r][c] = mfma16(afh[r], bfl[c], acc[r][c]);
            acc[r][c] = mfma16(afl[r], bfh[c], acc[r][c]);
        }
    }
    const bool valTile = (j0 >= 128 && j0 < 256);  // uniform per block
    #pragma unroll
    for (int r = 0; r < 2; r++)
    #pragma unroll
    for (int c = 0; c < 2; c++) {
        int j = j0 + wc + c * 16 + lr;
        float bias = bcat[j];
        #pragma unroll
        for (int q = 0; q < 4; q++) {
            int g = g0 + wr + r * 16 + 4 * lg + q;
            float v = acc[r][c][q] + bias;
            u16 h, l; split_hl(v, h, l);
            if (valTile) {
                int bb = g >> 9, n = g & 511;
                size_t off = ((size_t)(bb * 128 + (j - 128))) * 512 + n;
                VTH[off] = h; VTL[off] = l;
            } else {
                size_t off = (size_t)g * 1280 + j;
                CH[off] = h; CL[off] = l;
            }
        }
    }
}

// ---------------------------------------------------------------------------
// scores: att_raw[b,n,m] for a 64x64 tile. For each t: MFMA S_t tile @ dst^T,
// merge into sel where clamp(edge,0)==t (in-register gather). Then mask+leaky.
// ---------------------------------------------------------------------------
__launch_bounds__(256, 2)
__global__ void scores_kernel(const u16* __restrict__ CH, const u16* __restrict__ CL,
                              const void* __restrict__ Eptr, const int* __restrict__ flag,
                              float* __restrict__ att) {
    const int m0 = blockIdx.x * 64, n0 = blockIdx.y * 64, b = blockIdx.z;
    __shared__ u16 AH[64 * 128], AL[64 * 128], BH[64 * 128], BL[64 * 128];
    const int tid = threadIdx.x;
    const bool e64 = (*flag != 0);
    {   // stage B = dst rows m0..m0+63 (C cols 0..127)
        #pragma unroll
        for (int i = 0; i < 4; i++) {
            int idx = tid + i * 256;
            int row = idx >> 4, ch = idx & 15;
            size_t src = (size_t)(b * 512 + m0 + row) * 1280;
            int boff = (row * 256 + ch * 16) ^ ((row & 7) << 4);
            *(uint4*)((char*)BH + boff) = ((const uint4*)(CH + src))[ch];
            *(uint4*)((char*)BL + boff) = ((const uint4*)(CL + src))[ch];
        }
    }
    const int wid = tid >> 6, lane = tid & 63;
    const int wr = (wid >> 1) * 32, wc = (wid & 1) * 32;
    const int lr = lane & 15, lg = lane >> 4;
    int ed[2][2][4];
    #pragma unroll
    for (int r = 0; r < 2; r++)
    #pragma unroll
    for (int c = 0; c < 2; c++)
    #pragma unroll
    for (int q = 0; q < 4; q++) {
        long long n = n0 + wr + r * 16 + 4 * lg + q;
        long long m = m0 + wc + c * 16 + lr;
        long long idx = ((long long)b * 512 + n) * 512 + m;
        ed[r][c][q] = e64 ? (int)((const long long*)Eptr)[idx] : ((const int*)Eptr)[idx];
    }
    __syncthreads();
    bf16x8 bfh[4][2], bfl[4][2];           // dst fragments, reused across all t
    #pragma unroll
    for (int ks = 0; ks < 4; ks++) {
        const int kb2 = (ks * 32 + lg * 8) * 2;
        #pragma unroll
        for (int c = 0; c < 2; c++) {
            int row = wc + c * 16 + lr;
            int boff = (row * 256 + kb2) ^ ((row & 7) << 4);
            bfh[ks][c] = *(const bf16x8*)((const char*)BH + boff);
            bfl[ks][c] = *(const bf16x8*)((const char*)BL + boff);
        }
    }
    float sel[2][2][4];
    #pragma unroll
    for (int r = 0; r < 2; r++)
    #pragma unroll
    for (int c = 0; c < 2; c++)
    #pragma unroll
    for (int q = 0; q < 4; q++) sel[r][c][q] = 0.f;

    for (int t = 0; t < 8; t++) {
        __syncthreads();                   // previous A reads done
        #pragma unroll
        for (int i = 0; i < 4; i++) {      // stage A = S_t rows n0..n0+63
            int idx = tid + i * 256;
            int row = idx >> 4, ch = idx & 15;
            size_t src = (size_t)(b * 512 + n0 + row) * 1280 + 256 + t * 128;
            int boff = (row * 256 + ch * 16) ^ ((row & 7) << 4);
            *(uint4*)((char*)AH + boff) = ((const uint4*)(CH + src))[ch];
            *(uint4*)((char*)AL + boff) = ((const uint4*)(CL + src))[ch];
        }
        __syncthreads();
        f32x4 acc[2][2] = {};
        #pragma unroll
        for (int ks = 0; ks < 4; ks++) {
            const int kb2 = (ks * 32 + lg * 8) * 2;
            bf16x8 afh[2], afl[2];
            #pragma unroll
            for (int r = 0; r < 2; r++) {
                int row = wr + r * 16 + lr;
                int boff = (row * 256 + kb2) ^ ((row & 7) << 4);
                afh[r] = *(const bf16x8*)((const char*)AH + boff);
                afl[r] = *(const bf16x8*)((const char*)AL + boff);
            }
            #pragma unroll
            for (int r = 0; r < 2; r++)
            #pragma unroll
            for (int c = 0; c < 2; c++) {
                acc[r][c] = mfma16(afh[r], bfh[ks][c], acc[r][c]);
                acc[r][c] = mfma16(afh[r], bfl[ks][c], acc[r][c]);
                acc[r][c] = mfma16(afl[r], bfh[ks][c], acc[r][c]);
            }
        }
        #pragma unroll
        for (int r = 0; r < 2; r++)
        #pragma unroll
        for (int c = 0; c < 2; c++)
        #pragma unroll
        for (int q = 0; q < 4; q++) {
            int e = ed[r][c][q];
            int ec = e < 0 ? 0 : e;
            if (ec == t) sel[r][c][q] = acc[r][c][q];
        }
    }
    #pragma unroll
    for (int r = 0; r < 2; r++)
    #pragma unroll
    for (int c = 0; c < 2; c++)
    #pragma unroll
    for (int q = 0; q < 4; q++) {
        float v = (ed[r][c][q] == -1) ? -1e10f : sel[r][c][q];
        v = (v >= 0.f) ? v : 0.2f * v;     // leaky AFTER mask, like reference
        size_t n = n0 + wr + r * 16 + 4 * lg + q;
        size_t m = m0 + wc + c * 16 + lr;
        att[((size_t)b * 512 + n) * 512 + m] = v;
    }
}

// ---------------------------------------------------------------------------
// softmax: one block per row of 512. In-place repack: row bytes [0,1024) = hi
// bf16, [1024,2048) = lo bf16 of the probabilities.
// ---------------------------------------------------------------------------
__global__ void softmax_kernel(float* __restrict__ att) {
    const size_t row = blockIdx.x;
    float* p = att + row * 512;
    const int tid = threadIdx.x;
    float x0 = p[tid], x1 = p[tid + 256];
    float mx = fmaxf(x0, x1);
    #pragma unroll
    for (int o = 1; o < 64; o <<= 1) mx = fmaxf(mx, __shfl_xor(mx, o, 64));
    __shared__ float redm[4], reds[4];
    const int wid = tid >> 6;
    if ((tid & 63) == 0) redm[wid] = mx;
    __syncthreads();
    mx = fmaxf(fmaxf(redm[0], redm[1]), fmaxf(redm[2], redm[3]));
    float e0 = expf(x0 - mx), e1 = expf(x1 - mx);
    float s = e0 + e1;
    #pragma unroll
    for (int o = 1; o < 64; o <<= 1) s += __shfl_xor(s, o, 64);
    if ((tid & 63) == 0) reds[wid] = s;
    __syncthreads();
    s = reds[0] + reds[1] + reds[2] + reds[3];
    float inv = 1.0f / s;
    char* rb = (char*)att + row * 2048;
    u16 h, l;
    split_hl(e0 * inv, h, l);
    ((u16*)rb)[tid] = h; ((u16*)(rb + 1024))[tid] = l;
    split_hl(e1 * inv, h, l);
    ((u16*)rb)[tid + 256] = h; ((u16*)(rb + 1024))[tid + 256] = l;
}

// ---------------------------------------------------------------------------
// pv: tmp(b,n,d) = att @ val. Block 64n x 128d, K=512 in chunks of 64.
// A from packed softmax rows, B from pre-transposed valT. Output split hi/lo.
// ---------------------------------------------------------------------------
__launch_bounds__(256, 2)
__global__ void pv_kernel(const float* __restrict__ attP,
                          const u16* __restrict__ VTH, const u16* __restrict__ VTL,
                          u16* __restrict__ TH, u16* __restrict__ TL) {
    const int n0 = blockIdx.x * 64, b = blockIdx.y;
    __shared__ u16 AH[64 * 64], AL[64 * 64], BH[128 * 64], BL[128 * 64];
    const int tid = threadIdx.x;
    const int wid = tid >> 6, lane = tid & 63;
    const int wr = (wid >> 1) * 32, wc = (wid & 1) * 64;
    const int lr = lane & 15, lg = lane >> 4;
    f32x4 acc[2][4] = {};
    for (int mc = 0; mc < 8; mc++) {
        __syncthreads();
        const char* base = (const char*)attP;
        #pragma unroll
        for (int i = 0; i < 2; i++) {      // A: 64 rows x 64 m (hi+lo)
            int idx = tid + i * 256;
            int r = idx >> 3, ch = idx & 7;
            size_t rb = ((size_t)(b * 512 + n0 + r)) * 2048 + (size_t)mc * 128 + ch * 16;
            uint4 h = *(const uint4*)(base + rb);
            uint4 l = *(const uint4*)(base + rb + 1024);
            int boff = (r * 128 + ch * 16) ^ ((r & 7) << 4);
            *(uint4*)((char*)AH + boff) = h;
            *(uint4*)((char*)AL + boff) = l;
        }
        #pragma unroll
        for (int i = 0; i < 4; i++) {      // B: 128 d-rows x 64 m
            int idx = tid + i * 256;
            int r = idx >> 3, ch = idx & 7;
            size_t src = ((size_t)(b * 128 + r)) * 512 + mc * 64;
            int boff = (r * 128 + ch * 16) ^ ((r & 7) << 4);
            *(uint4*)((char*)BH + boff) = ((const uint4*)(VTH + src))[ch];
            *(uint4*)((char*)BL + boff) = ((const uint4*)(VTL + src))[ch];
        }
        __syncthreads();
        #pragma unroll
        for (int ks = 0; ks < 2; ks++) {
            const int kb2 = (ks * 32 + lg * 8) * 2;
            bf16x8 ah[2], al[2];
            #pragma unroll
            for (int r = 0; r < 2; r++) {
                int row = wr + r * 16 + lr;
                int boff = (row * 128 + kb2) ^ ((row & 7) << 4);
                ah[r] = *(const bf16x8*)((const char*)AH + boff);
                al[r] = *(const bf16x8*)((const char*)AL + boff);
            }
            #pragma unroll
            for (int c = 0; c < 4; c++) {
                int row = wc + c * 16 + lr;
                int boff = (row * 128 + kb2) ^ ((row & 7) << 4);
                bf16x8 bh = *(const bf16x8*)((const char*)BH + boff);
                bf16x8 bl = *(const bf16x8*)((const char*)BL + boff);
                #pragma unroll
                for (int r = 0; r < 2; r++) {
                    acc[r][c] = mfma16(ah[r], bh, acc[r][c]);
                    acc[r][c] = mfma16(ah[r], bl, acc[r][c]);
                    acc[r][c] = mfma16(al[r], bh, acc[r][c]);
                }
            }
        }
    }
    #pragma unroll
    for (int r = 0; r < 2; r++)
    #pragma unroll
    for (int c = 0; c < 4; c++)
    #pragma unroll
    for (int q = 0; q < 4; q++) {
        int g = b * 512 + n0 + wr + r * 16 + 4 * lg + q;
        int d = wc + c * 16 + lr;
        u16 h, l; split_hl(acc[r][c][q], h, l);
        size_t off = (size_t)g * 128 + d;
        TH[off] = h; TL[off] = l;
    }
}

// ---------------------------------------------------------------------------
// proj: out(16384x128) = tmp @ Pw^T + Pb (fp32 output to d_out).
// ---------------------------------------------------------------------------
__launch_bounds__(256, 2)
__global__ void proj_kernel(const u16* __restrict__ TH, const u16* __restrict__ TL,
                            const u16* __restrict__ WH, const u16* __restrict__ WL,
                            const float* __restrict__ bcat, float* __restrict__ out) {
    const int j0 = blockIdx.x * 64;
    const int g0 = blockIdx.y * 64;
    __shared__ u16 AH[64 * 128], AL[64 * 128], BH[64 * 128], BL[64 * 128];
    const int tid = threadIdx.x;
    {
        #pragma unroll
        for (int i = 0; i < 4; i++) {
            int idx = tid + i * 256;
            int row = idx >> 4, ch = idx & 15;
            int boff = (row * 256 + ch * 16) ^ ((row & 7) << 4);
            size_t asrc = (size_t)(g0 + row) * 128;
            *(uint4*)((char*)AH + boff) = ((const uint4*)(TH + asrc))[ch];
            *(uint4*)((char*)AL + boff) = ((const uint4*)(TL + asrc))[ch];
            size_t bsrc = (size_t)(1280 + j0 + row) * 128;
            *(uint4*)((char*)BH + boff) = ((const uint4*)(WH + bsrc))[ch];
            *(uint4*)((char*)BL + boff) = ((const uint4*)(WL + bsrc))[ch];
        }
    }
    __syncthreads();
    const int wid = tid >> 6, lane = tid & 63;
    const int wr = (wid >> 1) * 32, wc = (wid & 1) * 32;
    const int lr = lane & 15, lg = lane >> 4;
    f32x4 acc[2][2] = {};
    #pragma unroll
    for (int ks = 0; ks < 4; ks++) {
        const int kb2 = (ks * 32 + lg * 8) * 2;
        bf16x8 afh[2], afl[2], bfh[2], bfl[2];
        #pragma unroll
        for (int r = 0; r < 2; r++) {
            int row = wr + r * 16 + lr;
            int boff = (row * 256 + kb2) ^ ((row & 7) << 4);
            afh[r] = *(const bf16x8*)((const char*)AH + boff);
            afl[r] = *(const bf16x8*)((const char*)AL + boff);
        }
        #pragma unroll
        for (int c = 0; c < 2; c++) {
            int row = wc + c * 16 + lr;
            int boff = (row * 256 + kb2) ^ ((row & 7) << 4);
            bfh[c] = *(const bf16x8*)((const char*)BH + boff);
            bfl[c] = *(const bf16x8*)((const char*)BL + boff);
        }
        #pragma unroll
        for (int r = 0; r < 2; r++)
        #pragma unroll
        for (int c = 0; c < 2; c++) {
            acc[r][c] = mfma16(afh[r], bfh[c], acc[r][c]);
            acc[r][c] = mfma16(afh[r], bfl[c], acc[r][c]);
            acc[r][c] = mfma16(afl[r], bfh[c], acc[r][c]);
        }
    }
    #pragma unroll
    for (int r = 0; r < 2; r++)
    #pragma unroll
    for (int c = 0; c < 2; c++) {
        int j = j0 + wc + c * 16 + lr;
        float bias = bcat[1280 + j];
        #pragma unroll
        for (int q = 0; q < 4; q++) {
            int g = g0 + wr + r * 16 + 4 * lg + q;
            out[(size_t)g * 128 + j] = acc[r][c][q] + bias;
        }
    }
}

extern "C" void kernel_launch(void* const* d_in, const int* in_sizes, int n_in,
                              void* d_out, int out_size, void* d_ws, size_t ws_size,
                              hipStream_t stream) {
    (void)in_sizes; (void)n_in; (void)out_size; (void)ws_size;
    const float* X  = (const float*)d_in[0];
    const void*  E  = d_in[1];
    const float* Qw = (const float*)d_in[2];
    const float* Qb = (const float*)d_in[3];
    const float* Kw = (const float*)d_in[4];
    const float* Kb = (const float*)d_in[5];
    const float* Vw = (const float*)d_in[6];
    const float* Vb = (const float*)d_in[7];
    const float* Aa = (const float*)d_in[8];
    const float* Pw = (const float*)d_in[9];
    const float* Pb = (const float*)d_in[10];
    float* out = (float*)d_out;

    char* ws = (char*)d_ws;
    size_t cur = 0;
    auto alloc = [&](size_t bytes) -> char* {
        char* p = ws + cur;
        cur += (bytes + 255) & ~(size_t)255;
        return p;
    };
    int*   flag = (int*)  alloc(4);
    u16*   WH   = (u16*)  alloc((size_t)1408 * 128 * 2);
    u16*   WL   = (u16*)  alloc((size_t)1408 * 128 * 2);
    float* bcat = (float*)alloc(1408 * 4);
    u16*   CH   = (u16*)  alloc((size_t)16384 * 1280 * 2);
    u16*   CL   = (u16*)  alloc((size_t)16384 * 1280 * 2);
    u16*   VTH  = (u16*)  alloc((size_t)32 * 128 * 512 * 2);
    u16*   VTL  = (u16*)  alloc((size_t)32 * 128 * 512 * 2);
    float* att  = (float*)alloc((size_t)32 * 512 * 512 * 4);
    u16*   TH   = (u16*)  alloc((size_t)16384 * 128 * 2);
    u16*   TL   = (u16*)  alloc((size_t)16384 * 128 * 2);

    prep_kernel<<<704, 256, 0, stream>>>(Qw, Qb, Kw, Kb, Vw, Vb, Aa, Pw, Pb, WH, WL, bcat);
    detect_kernel<<<1, 256, 0, stream>>>((const int*)E, flag);
    gemm1_kernel<<<dim3(20, 256), 256, 0, stream>>>(X, WH, WL, bcat, CH, CL, VTH, VTL);
    scores_kernel<<<dim3(8, 8, 32), 256, 0, stream>>>(CH, CL, E, flag, att);
    softmax_kernel<<<16384, 256, 0, stream>>>(att);
    pv_kernel<<<dim3(8, 32), 256, 0, stream>>>(att, VTH, VTL, TH, TL);
    proj_kernel<<<dim3(2, 256), 256, 0, stream>>>(TH, TL, WH, WL, bcat, out);
}

// Round 2
// 249.169 us; speedup vs baseline: 1.1811x; 1.1811x over previous
//
#include <hip/hip_runtime.h>
#include <stdint.h>

// GeAT single-head layer, B=32 N=512 D=128 T=8.
// S_t = X @ (Qw^T a_t) + (Qb a_t);  dst = X@Kw^T+Kb
// VP  = X @ (Pw Vw)^T + Pw Vb      (Pw folded into val projection!)
// att_raw[b,n,m] = S_{clamp(e,0)}[b,n,:] . dst[b,m,:] -> mask -> leaky -> softmax
// out = att @ VP + Pb
// All matmuls fp32-emulated: hi/lo bf16 split, 3x mfma_f32_16x16x32_bf16.

typedef short bf16x8 __attribute__((ext_vector_type(8)));
typedef float f32x4 __attribute__((ext_vector_type(4)));
typedef unsigned short u16;
typedef unsigned int u32;

__device__ __forceinline__ u16 f2bf(float x) {
    union { float f; u32 u; } v; v.f = x;
    u32 r = v.u + 0x7FFFu + ((v.u >> 16) & 1u);
    return (u16)(r >> 16);
}
__device__ __forceinline__ float bf2f(u16 h) {
    union { u32 u; float f; } v; v.u = ((u32)h) << 16; return v.f;
}
__device__ __forceinline__ void split_hl(float x, u16& h, u16& l) {
    h = f2bf(x);
    l = f2bf(x - bf2f(h));
}
__device__ __forceinline__ f32x4 mfma16(bf16x8 a, bf16x8 b, f32x4 c) {
    return __builtin_amdgcn_mfma_f32_16x16x32_bf16(a, b, c, 0, 0, 0);
}

// ---------------------------------------------------------------------------
// prep: WcatT (1280 x 128) hi/lo bf16 + bcat (1280) f32.
// rows [0,128): Kw (dst) | [128,256): Pw@Vw (VP) | [256,1280): (Qw^T a_t) cols
// ---------------------------------------------------------------------------
__global__ void prep_kernel(const float* __restrict__ Qw, const float* __restrict__ Qb,
                            const float* __restrict__ Kw, const float* __restrict__ Kb,
                            const float* __restrict__ Vw, const float* __restrict__ Vb,
                            const float* __restrict__ Aa, const float* __restrict__ Pw,
                            u16* __restrict__ WH, u16* __restrict__ WL,
                            float* __restrict__ bcat) {
    int gid = blockIdx.x * 256 + threadIdx.x;
    if (gid >= 1280 * 128) return;
    int j = gid >> 7, d = gid & 127;
    float v, bias = 0.f;
    if (j < 128) { v = Kw[j * 128 + d]; bias = Kb[j]; }
    else if (j < 256) {
        int jj = j - 128;
        float s = 0.f, bs = 0.f;
        for (int k = 0; k < 128; k++) {
            float p = Pw[jj * 128 + k];
            s += p * Vw[k * 128 + d];
            bs += p * Vb[k];
        }
        v = s; bias = bs;
    } else {
        int r = j - 256, t = r >> 7, jj = r & 127;
        float s = 0.f, bs = 0.f;
        for (int e = 0; e < 128; e++) {
            float av = Aa[(e * 128 + jj) * 8 + t];
            s += Qw[e * 128 + d] * av;
            bs += Qb[e] * av;
        }
        v = s; bias = bs;
    }
    u16 h, l; split_hl(v, h, l);
    WH[gid] = h; WL[gid] = l;
    if (d == 0) bcat[j] = bias;
}

// ---------------------------------------------------------------------------
// detect: int32 vs int64 edge layout (odd words of int64 small values are 0/-1)
// ---------------------------------------------------------------------------
__global__ void detect_kernel(const int* __restrict__ E, int* __restrict__ flag) {
    __shared__ int bad;
    if (threadIdx.x == 0) bad = 0;
    __syncthreads();
    int w0 = E[2 * threadIdx.x + 1];
    int w1 = E[2 * (threadIdx.x + 256) + 1];
    if (!(w0 == 0 || w0 == -1) || !(w1 == 0 || w1 == -1)) atomicOr(&bad, 1);
    __syncthreads();
    if (threadIdx.x == 0) *flag = (bad ? 0 : 1);
}

// ---------------------------------------------------------------------------
// econv: edges -> int8 (8.4 MB instead of 67 MB in the hot scores kernel)
// ---------------------------------------------------------------------------
__global__ void econv_kernel(const void* __restrict__ E, const int* __restrict__ flag,
                             signed char* __restrict__ E8) {
    int i = (blockIdx.x * 256 + threadIdx.x) * 4;
    char4 o;
    if (*flag) {
        const long long* p = (const long long*)E;
        o.x = (signed char)p[i]; o.y = (signed char)p[i + 1];
        o.z = (signed char)p[i + 2]; o.w = (signed char)p[i + 3];
    } else {
        const int* p = (const int*)E;
        o.x = (signed char)p[i]; o.y = (signed char)p[i + 1];
        o.z = (signed char)p[i + 2]; o.w = (signed char)p[i + 3];
    }
    *(char4*)(E8 + i) = o;
}

// ---------------------------------------------------------------------------
// gemm1: C(16384 x 1280) = X @ WcatT^T + bcat (hi/lo). VP cols [128,256) go
// transposed into VTH/VTL (B,128,512). XCD swizzle groups 20 j-tiles per g.
// ---------------------------------------------------------------------------
__launch_bounds__(256, 2)
__global__ void gemm1_kernel(const float* __restrict__ X,
                             const u16* __restrict__ WH, const u16* __restrict__ WL,
                             const float* __restrict__ bcat,
                             u16* __restrict__ CH, u16* __restrict__ CL,
                             u16* __restrict__ VTH, u16* __restrict__ VTL) {
    const int id = blockIdx.x;
    const int xcd = id & 7, q5 = id >> 3;
    const int g = xcd * 32 + q5 / 20;
    const int jt = q5 - (q5 / 20) * 20;
    const int j0 = jt * 64;
    const int g0 = g * 64;
    __shared__ u16 AH[64 * 128], AL[64 * 128], BH[64 * 128], BL[64 * 128];
    const int tid = threadIdx.x;
    {
        const float4* Xv = (const float4*)(X + (size_t)g0 * 128);
        #pragma unroll
        for (int i = 0; i < 8; i++) {
            int idx = tid + i * 256;
            float4 x = Xv[idx];
            int row = idx >> 5, c4 = idx & 31;
            int boff = (row * 256 + c4 * 8) ^ ((row & 7) << 4);
            u16* ph = (u16*)((char*)AH + boff);
            u16* pl = (u16*)((char*)AL + boff);
            const float* xf = (const float*)&x;
            #pragma unroll
            for (int q = 0; q < 4; q++) { u16 h, l; split_hl(xf[q], h, l); ph[q] = h; pl[q] = l; }
        }
        const uint4* bh = (const uint4*)(WH + (size_t)j0 * 128);
        const uint4* bl = (const uint4*)(WL + (size_t)j0 * 128);
        #pragma unroll
        for (int i = 0; i < 4; i++) {
            int idx = tid + i * 256;
            int row = idx >> 4, ch = idx & 15;
            int boff = (row * 256 + ch * 16) ^ ((row & 7) << 4);
            *(uint4*)((char*)BH + boff) = bh[idx];
            *(uint4*)((char*)BL + boff) = bl[idx];
        }
    }
    __syncthreads();
    const int wid = tid >> 6, lane = tid & 63;
    const int wr = (wid >> 1) * 32, wc = (wid & 1) * 32;
    const int lr = lane & 15, lg = lane >> 4;
    f32x4 acc[2][2] = {};
    #pragma unroll
    for (int ks = 0; ks < 4; ks++) {
        const int kb2 = (ks * 32 + lg * 8) * 2;
        bf16x8 afh[2], afl[2], bfh[2], bfl[2];
        #pragma unroll
        for (int r = 0; r < 2; r++) {
            int row = wr + r * 16 + lr;
            int boff = (row * 256 + kb2) ^ ((row & 7) << 4);
            afh[r] = *(const bf16x8*)((const char*)AH + boff);
            afl[r] = *(const bf16x8*)((const char*)AL + boff);
        }
        #pragma unroll
        for (int c = 0; c < 2; c++) {
            int row = wc + c * 16 + lr;
            int boff = (row * 256 + kb2) ^ ((row & 7) << 4);
            bfh[c] = *(const bf16x8*)((const char*)BH + boff);
            bfl[c] = *(const bf16x8*)((const char*)BL + boff);
        }
        #pragma unroll
        for (int r = 0; r < 2; r++)
        #pragma unroll
        for (int c = 0; c < 2; c++) {
            acc[r][c] = mfma16(afh[r], bfh[c], acc[r][c]);
            acc[r][c] = mfma16(afh[r], bfl[c], acc[r][c]);
            acc[r][c] = mfma16(afl[r], bfh[c], acc[r][c]);
        }
    }
    const bool valTile = (j0 >= 128 && j0 < 256);
    #pragma unroll
    for (int r = 0; r < 2; r++)
    #pragma unroll
    for (int c = 0; c < 2; c++) {
        int j = j0 + wc + c * 16 + lr;
        float bias = bcat[j];
        #pragma unroll
        for (int q = 0; q < 4; q++) {
            int g1 = g0 + wr + r * 16 + 4 * lg + q;
            float v = acc[r][c][q] + bias;
            u16 h, l; split_hl(v, h, l);
            if (valTile) {
                int bb = g1 >> 9, n = g1 & 511;
                size_t off = ((size_t)(bb * 128 + (j - 128))) * 512 + n;
                VTH[off] = h; VTL[off] = l;
            } else {
                size_t off = (size_t)g1 * 1280 + j;
                CH[off] = h; CL[off] = l;
            }
        }
    }
}

// ---------------------------------------------------------------------------
// scores: 64n x 128m tile, 512 thr / 8 waves. dst fragments register-resident
// across all 8 types; A (S_t) double-buffered with async global->reg->LDS
// prefetch; one barrier per t. XCD-bijective swizzle: 4 m-blocks of each
// (n0,b) pair land on the same XCD (S-tile L2 reuse), 4 b's per XCD.
// ---------------------------------------------------------------------------
__launch_bounds__(512, 2)
__global__ void scores_kernel(const u16* __restrict__ CH, const u16* __restrict__ CL,
                              const signed char* __restrict__ E8,
                              float* __restrict__ att) {
    const int id = blockIdx.x;
    const int xcd = id & 7, j = id >> 3;
    const int m0 = (j & 3) * 128;
    const int pair = xcd * 32 + (j >> 2);
    const int n0 = (pair & 7) * 64, b = pair >> 3;
    __shared__ u16 BH[128 * 128], BL[128 * 128];      // dst tile, 32 KB each
    __shared__ u16 AH[2][64 * 128], AL[2][64 * 128];  // S_t dbuf, 16 KB each
    const int tid = threadIdx.x;
    const int wid = tid >> 6, lane = tid & 63;
    const int wr = (wid >> 2) * 32, wc = (wid & 3) * 32;
    const int lr = lane & 15, lg = lane >> 4;

    // stage B = dst rows m0..m0+127
    #pragma unroll
    for (int i = 0; i < 4; i++) {
        int idx = tid + i * 512;
        int row = idx >> 4, ch = idx & 15;
        size_t src = (size_t)(b * 512 + m0 + row) * 1280;
        int boff = (row * 256 + ch * 16) ^ ((row & 7) << 4);
        *(uint4*)((char*)BH + boff) = ((const uint4*)(CH + src))[ch];
        *(uint4*)((char*)BL + boff) = ((const uint4*)(CL + src))[ch];
    }
    // edges (int8)
    int ed[2][2][4];
    #pragma unroll
    for (int r = 0; r < 2; r++)
    #pragma unroll
    for (int c = 0; c < 2; c++)
    #pragma unroll
    for (int q = 0; q < 4; q++) {
        int n = n0 + wr + r * 16 + 4 * lg + q;
        int m = m0 + wc + c * 16 + lr;
        ed[r][c][q] = E8[((size_t)b * 512 + n) * 512 + m];
    }
    // prefetch A(t=0) into regs, write to buf0
    uint4 rh[2], rl[2];
    {
        #pragma unroll
        for (int i = 0; i < 2; i++) {
            int idx = tid + i * 512;
            int row = idx >> 4, ch = idx & 15;
            size_t src = (size_t)(b * 512 + n0 + row) * 1280 + 256;
            rh[i] = ((const uint4*)(CH + src))[ch];
            rl[i] = ((const uint4*)(CL + src))[ch];
        }
        #pragma unroll
        for (int i = 0; i < 2; i++) {
            int idx = tid + i * 512;
            int row = idx >> 4, ch = idx & 15;
            int boff = (row * 256 + ch * 16) ^ ((row & 7) << 4);
            *(uint4*)((char*)AH[0] + boff) = rh[i];
            *(uint4*)((char*)AL[0] + boff) = rl[i];
        }
    }
    __syncthreads();
    // dst fragments: register-resident for all 8 t
    bf16x8 bfh[4][2], bfl[4][2];
    #pragma unroll
    for (int ks = 0; ks < 4; ks++) {
        const int kb2 = (ks * 32 + lg * 8) * 2;
        #pragma unroll
        for (int c = 0; c < 2; c++) {
            int row = wc + c * 16 + lr;
            int boff = (row * 256 + kb2) ^ ((row & 7) << 4);
            bfh[ks][c] = *(const bf16x8*)((const char*)BH + boff);
            bfl[ks][c] = *(const bf16x8*)((const char*)BL + boff);
        }
    }
    float sel[2][2][4];
    #pragma unroll
    for (int r = 0; r < 2; r++)
    #pragma unroll
    for (int c = 0; c < 2; c++)
    #pragma unroll
    for (int q = 0; q < 4; q++) sel[r][c][q] = 0.f;

    for (int t = 0; t < 8; t++) {
        const int cur = t & 1;
        uint4 nh[2], nl[2];
        if (t < 7) {                       // issue next-t loads early (T14)
            #pragma unroll
            for (int i = 0; i < 2; i++) {
                int idx = tid + i * 512;
                int row = idx >> 4, ch = idx & 15;
                size_t src = (size_t)(b * 512 + n0 + row) * 1280 + 256 + (t + 1) * 128;
                nh[i] = ((const uint4*)(CH + src))[ch];
                nl[i] = ((const uint4*)(CL + src))[ch];
            }
        }
        f32x4 acc[2][2] = {};
        #pragma unroll
        for (int ks = 0; ks < 4; ks++) {
            const int kb2 = (ks * 32 + lg * 8) * 2;
            bf16x8 afh[2], afl[2];
            #pragma unroll
            for (int r = 0; r < 2; r++) {
                int row = wr + r * 16 + lr;
                int boff = (row * 256 + kb2) ^ ((row & 7) << 4);
                afh[r] = *(const bf16x8*)((const char*)AH[cur] + boff);
                afl[r] = *(const bf16x8*)((const char*)AL[cur] + boff);
            }
            #pragma unroll
            for (int r = 0; r < 2; r++)
            #pragma unroll
            for (int c = 0; c < 2; c++) {
                acc[r][c] = mfma16(afh[r], bfh[ks][c], acc[r][c]);
                acc[r][c] = mfma16(afh[r], bfl[ks][c], acc[r][c]);
                acc[r][c] = mfma16(afl[r], bfh[ks][c], acc[r][c]);
            }
        }
        #pragma unroll
        for (int r = 0; r < 2; r++)
        #pragma unroll
        for (int c = 0; c < 2; c++)
        #pragma unroll
        for (int q = 0; q < 4; q++) {
            int ec = ed[r][c][q] < 0 ? 0 : ed[r][c][q];
            sel[r][c][q] = (ec == t) ? acc[r][c][q] : sel[r][c][q];
        }
        if (t < 7) {                       // land prefetch into other buffer
            #pragma unroll
            for (int i = 0; i < 2; i++) {
                int idx = tid + i * 512;
                int row = idx >> 4, ch = idx & 15;
                int boff = (row * 256 + ch * 16) ^ ((row & 7) << 4);
                *(uint4*)((char*)AH[cur ^ 1] + boff) = nh[i];
                *(uint4*)((char*)AL[cur ^ 1] + boff) = nl[i];
            }
        }
        __syncthreads();
    }
    #pragma unroll
    for (int r = 0; r < 2; r++)
    #pragma unroll
    for (int c = 0; c < 2; c++)
    #pragma unroll
    for (int q = 0; q < 4; q++) {
        float v = (ed[r][c][q] == -1) ? -1e10f : sel[r][c][q];
        v = (v >= 0.f) ? v : 0.2f * v;
        size_t n = n0 + wr + r * 16 + 4 * lg + q;
        size_t m = m0 + wc + c * 16 + lr;
        att[((size_t)b * 512 + n) * 512 + m] = v;
    }
}

// ---------------------------------------------------------------------------
// out: fused softmax + (att @ VP) + Pb. 32n x 128d per block, 256 thr.
// Phase 1: row max + exp-sum. Phase 2: per 64-m chunk, exp-normalize into
// LDS (hi/lo) and MFMA against VP^T chunk. Same-b blocks colocate per XCD.
// ---------------------------------------------------------------------------
__launch_bounds__(256, 4)
__global__ void out_kernel(const float* __restrict__ att,
                           const u16* __restrict__ VTH, const u16* __restrict__ VTL,
                           const float* __restrict__ Pb, float* __restrict__ out) {
    const int id = blockIdx.x;
    const int xcd = id & 7, j = id >> 3;
    const int b = xcd * 4 + (j >> 4);
    const int n0 = (j & 15) * 32;
    __shared__ u16 PH[32 * 64], PL[32 * 64];    // 4 KB each
    __shared__ u16 VH[128 * 64], VL[128 * 64];  // 16 KB each
    __shared__ float smx[32], sinv[32];
    const int tid = threadIdx.x;
    const int wid = tid >> 6, lane = tid & 63;
    // phase 1: row max + sum(exp)
    #pragma unroll
    for (int rr = 0; rr < 8; rr++) {
        int row = wid * 8 + rr;
        const float* rp = att + ((size_t)b * 512 + n0 + row) * 512;
        float4 a0 = ((const float4*)rp)[lane * 2];
        float4 a1 = ((const float4*)rp)[lane * 2 + 1];
        float mx = fmaxf(fmaxf(fmaxf(a0.x, a0.y), fmaxf(a0.z, a0.w)),
                         fmaxf(fmaxf(a1.x, a1.y), fmaxf(a1.z, a1.w)));
        #pragma unroll
        for (int o = 1; o < 64; o <<= 1) mx = fmaxf(mx, __shfl_xor(mx, o, 64));
        float s = expf(a0.x - mx) + expf(a0.y - mx) + expf(a0.z - mx) + expf(a0.w - mx)
                + expf(a1.x - mx) + expf(a1.y - mx) + expf(a1.z - mx) + expf(a1.w - mx);
        #pragma unroll
        for (int o = 1; o < 64; o <<= 1) s += __shfl_xor(s, o, 64);
        if (lane == 0) { smx[row] = mx; sinv[row] = 1.0f / s; }
    }
    __syncthreads();
    const int lr = lane & 15, lg = lane >> 4;
    const int wc = wid * 32;
    f32x4 acc[2][2] = {};
    for (int mc = 0; mc < 8; mc++) {
        {   // stage P chunk: exp-normalize + hilo split
            int row = tid >> 3, c8 = tid & 7;
            const float* rp = att + ((size_t)b * 512 + n0 + row) * 512 + mc * 64 + c8 * 8;
            float4 a0 = ((const float4*)rp)[0];
            float4 a1 = ((const float4*)rp)[1];
            float mxv = smx[row], iv = sinv[row];
            union { u16 us[8]; uint4 v; } uh, ul;
            float xs[8] = {a0.x, a0.y, a0.z, a0.w, a1.x, a1.y, a1.z, a1.w};
            #pragma unroll
            for (int q = 0; q < 8; q++) {
                float p = expf(xs[q] - mxv) * iv;
                split_hl(p, uh.us[q], ul.us[q]);
            }
            int boff = (row * 128 + c8 * 16) ^ ((row & 7) << 4);
            *(uint4*)((char*)PH + boff) = uh.v;
            *(uint4*)((char*)PL + boff) = ul.v;
        }
        #pragma unroll
        for (int i = 0; i < 4; i++) {   // stage V chunk (128 d x 64 m)
            int idx = tid + i * 256;
            int row = idx >> 3, ch = idx & 7;
            size_t src = ((size_t)(b * 128 + row)) * 512 + mc * 64;
            int boff = (row * 128 + ch * 16) ^ ((row & 7) << 4);
            *(uint4*)((char*)VH + boff) = ((const uint4*)(VTH + src))[ch];
            *(uint4*)((char*)VL + boff) = ((const uint4*)(VTL + src))[ch];
        }
        __syncthreads();
        #pragma unroll
        for (int ks = 0; ks < 2; ks++) {
            const int kb2 = (ks * 32 + lg * 8) * 2;
            bf16x8 ah[2], al[2];
            #pragma unroll
            for (int r = 0; r < 2; r++) {
                int row = r * 16 + lr;
                int boff = (row * 128 + kb2) ^ ((row & 7) << 4);
                ah[r] = *(const bf16x8*)((const char*)PH + boff);
                al[r] = *(const bf16x8*)((const char*)PL + boff);
            }
            #pragma unroll
            for (int c = 0; c < 2; c++) {
                int row = wc + c * 16 + lr;
                int boff = (row * 128 + kb2) ^ ((row & 7) << 4);
                bf16x8 bh = *(const bf16x8*)((const char*)VH + boff);
                bf16x8 bl = *(const bf16x8*)((const char*)VL + boff);
                #pragma unroll
                for (int r = 0; r < 2; r++) {
                    acc[r][c] = mfma16(ah[r], bh, acc[r][c]);
                    acc[r][c] = mfma16(ah[r], bl, acc[r][c]);
                    acc[r][c] = mfma16(al[r], bh, acc[r][c]);
                }
            }
        }
        __syncthreads();
    }
    #pragma unroll
    for (int r = 0; r < 2; r++)
    #pragma unroll
    for (int c = 0; c < 2; c++)
    #pragma unroll
    for (int q = 0; q < 4; q++) {
        int n = n0 + r * 16 + 4 * lg + q;
        int d = wc + c * 16 + lr;
        out[((size_t)b * 512 + n) * 128 + d] = acc[r][c][q] + Pb[d];
    }
}

extern "C" void kernel_launch(void* const* d_in, const int* in_sizes, int n_in,
                              void* d_out, int out_size, void* d_ws, size_t ws_size,
                              hipStream_t stream) {
    (void)in_sizes; (void)n_in; (void)out_size; (void)ws_size;
    const float* X  = (const float*)d_in[0];
    const void*  E  = d_in[1];
    const float* Qw = (const float*)d_in[2];
    const float* Qb = (const float*)d_in[3];
    const float* Kw = (const float*)d_in[4];
    const float* Kb = (const float*)d_in[5];
    const float* Vw = (const float*)d_in[6];
    const float* Vb = (const float*)d_in[7];
    const float* Aa = (const float*)d_in[8];
    const float* Pw = (const float*)d_in[9];
    const float* Pb = (const float*)d_in[10];
    float* out = (float*)d_out;

    char* ws = (char*)d_ws;
    size_t cur = 0;
    auto alloc = [&](size_t bytes) -> char* {
        char* p = ws + cur;
        cur += (bytes + 255) & ~(size_t)255;
        return p;
    };
    int*   flag = (int*)  alloc(4);
    u16*   WH   = (u16*)  alloc((size_t)1280 * 128 * 2);
    u16*   WL   = (u16*)  alloc((size_t)1280 * 128 * 2);
    float* bcat = (float*)alloc(1280 * 4);
    u16*   CH   = (u16*)  alloc((size_t)16384 * 1280 * 2);
    u16*   CL   = (u16*)  alloc((size_t)16384 * 1280 * 2);
    u16*   VTH  = (u16*)  alloc((size_t)32 * 128 * 512 * 2);
    u16*   VTL  = (u16*)  alloc((size_t)32 * 128 * 512 * 2);
    float* att  = (float*)alloc((size_t)32 * 512 * 512 * 4);
    signed char* E8 = (signed char*)alloc((size_t)32 * 512 * 512);

    prep_kernel<<<640, 256, 0, stream>>>(Qw, Qb, Kw, Kb, Vw, Vb, Aa, Pw, WH, WL, bcat);
    detect_kernel<<<1, 256, 0, stream>>>((const int*)E, flag);
    econv_kernel<<<8192, 256, 0, stream>>>(E, flag, E8);
    gemm1_kernel<<<5120, 256, 0, stream>>>(X, WH, WL, bcat, CH, CL, VTH, VTL);
    scores_kernel<<<1024, 512, 0, stream>>>(CH, CL, E8, att);
    out_kernel<<<512, 256, 0, stream>>>(att, VTH, VTL, Pb, out);
}